// Round 3
// baseline (203.451 us; speedup 1.0000x reference)
//
#include <hip/hip_runtime.h>
#include <stdint.h>

typedef __attribute__((ext_vector_type(8))) short bf16x8;
typedef __attribute__((ext_vector_type(4))) short bf16x4;
typedef __attribute__((ext_vector_type(4))) float f32x4;

#define WAVES 8
#define R_STRIDE 72                    // 64 + 8 pad elems -> 144 B rows (16B aligned)
#define A_STRIDE 40                    // 32 + 8 pad elems -> 80 B rows (16B aligned)
#define R_LDS_SHORTS (32 * R_STRIDE)   // 2304
#define A_LDS_SHORTS (32 * A_STRIDE)   // 1280
#define WAVE_LDS (R_LDS_SHORTS + A_LDS_SHORTS)  // 3584 shorts = 7168 B per wave
#define VB_STRIDE 68                   // padded fp32 row stride for reduction buffers

static __device__ __forceinline__ unsigned short f2bf(float f) {
    union { float f; unsigned int i; } x; x.f = f;
    unsigned int i = x.i;
    return (unsigned short)((i + 0x7FFFu + ((i >> 16) & 1u)) >> 16);  // RNE
}

static __device__ __forceinline__ bf16x8 cvt8(float4 a, float4 b) {
    bf16x8 r;
    r[0] = (short)f2bf(a.x); r[1] = (short)f2bf(a.y);
    r[2] = (short)f2bf(a.z); r[3] = (short)f2bf(a.w);
    r[4] = (short)f2bf(b.x); r[5] = (short)f2bf(b.y);
    r[6] = (short)f2bf(b.z); r[7] = (short)f2bf(b.w);
    return r;
}

// One block per m (B*T = 256). 512 threads = 8 waves; each wave processes 32-row
// n-chunks: fp32 global loads -> bf16 frags, GEMM1 (logits) vs resident W frags,
// softmax in-register, a -> LDS -> A-frag transform, GEMM2 accumulates v.
// Output written as fp32 (reference output dtype).
__global__ __launch_bounds__(512, 2)
void netvlad_fused(const float* __restrict__ R,
                   const float* __restrict__ W,
                   const float* __restrict__ bias,
                   const float* __restrict__ cent,
                   float* __restrict__ out)
{
    __shared__ short smem[WAVES * WAVE_LDS];   // 57344 B; reused as fp32 reduction bufs
    __shared__ float suma_buf[4][32];

    const int tid  = threadIdx.x;
    const int wave = tid >> 6;
    const int lane = tid & 63;
    const int l15  = lane & 15;
    const int quad = lane >> 4;
    const int m    = blockIdx.x;

    short* r_lds = smem + wave * WAVE_LDS;
    short* a_lds = r_lds + R_LDS_SHORTS;

    const float* Rm = R + (size_t)m * (2048 * 64);

    // W fragments (B-operand of GEMM1): B[kdim=c][col=k] -> lane reads W row
    // (kt*16+l15), cols cc*32+quad*8..+7 : two float4 loads, convert to bf16.
    bf16x8 wf[2][2];
#pragma unroll
    for (int kt = 0; kt < 2; ++kt)
#pragma unroll
        for (int cc = 0; cc < 2; ++cc) {
            const float* wp = W + (kt*16 + l15)*64 + cc*32 + quad*8;
            wf[kt][cc] = cvt8(*(const float4*)wp, *(const float4*)(wp + 4));
        }

    float bval[2];
    bval[0] = bias[l15];
    bval[1] = bias[16 + l15];

    f32x4 acc[2][4];   // v accumulator tiles [ktile][ctile], D-layout
#pragma unroll
    for (int kt = 0; kt < 2; ++kt)
#pragma unroll
        for (int ct = 0; ct < 4; ++ct)
            acc[kt][ct] = (f32x4){0.f, 0.f, 0.f, 0.f};
    float suma[2] = {0.f, 0.f};

    // prefetch iter 0 (wave w starts at rows w*32): raw fp32, [s][cc][half]
    float4 cur[2][2][2];
#pragma unroll
    for (int s = 0; s < 2; ++s)
#pragma unroll
        for (int cc = 0; cc < 2; ++cc) {
            const float* rp = Rm + (size_t)(wave*32 + s*16 + l15)*64 + cc*32 + quad*8;
            cur[s][cc][0] = *(const float4*)rp;
            cur[s][cc][1] = *(const float4*)(rp + 4);
        }

#pragma unroll
    for (int it = 0; it < 8; ++it) {
        float4 nxt[2][2][2];
        if (it < 7) {
            const int n0n = ((it+1)*WAVES + wave) * 32;
#pragma unroll
            for (int s = 0; s < 2; ++s)
#pragma unroll
                for (int cc = 0; cc < 2; ++cc) {
                    const float* rp = Rm + (size_t)(n0n + s*16 + l15)*64 + cc*32 + quad*8;
                    nxt[s][cc][0] = *(const float4*)rp;
                    nxt[s][cc][1] = *(const float4*)(rp + 4);
                }
        }

        // convert to bf16 A-frags and stage r tile to per-wave LDS
        bf16x8 af[2][2];
#pragma unroll
        for (int s = 0; s < 2; ++s)
#pragma unroll
            for (int cc = 0; cc < 2; ++cc) {
                af[s][cc] = cvt8(cur[s][cc][0], cur[s][cc][1]);
                *(bf16x8*)(r_lds + (s*16 + l15)*R_STRIDE + cc*32 + quad*8) = af[s][cc];
            }

        // GEMM1: logits (32 rows x 32 k), 8 MFMAs
        f32x4 d1[2][2];
#pragma unroll
        for (int s = 0; s < 2; ++s)
#pragma unroll
            for (int kt = 0; kt < 2; ++kt) {
                f32x4 d = (f32x4){0.f, 0.f, 0.f, 0.f};
                d = __builtin_amdgcn_mfma_f32_16x16x32_bf16(af[s][0], wf[kt][0], d, 0, 0, 0);
                d = __builtin_amdgcn_mfma_f32_16x16x32_bf16(af[s][1], wf[kt][1], d, 0, 0, 0);
                d1[s][kt] = d;
            }

        // softmax over k (row = s*16 + quad*4 + r, k = kt*16 + l15)
#pragma unroll
        for (int s = 0; s < 2; ++s) {
            bf16x4 p0, p1;
            float a0s = 0.f, a1s = 0.f;
#pragma unroll
            for (int r = 0; r < 4; ++r) {
                float l0 = d1[s][0][r] + bval[0];
                float l1 = d1[s][1][r] + bval[1];
                float e0 = __expf(l0);
                float e1 = __expf(l1);
                float ss = e0 + e1;
                ss += __shfl_xor(ss, 1);
                ss += __shfl_xor(ss, 2);
                ss += __shfl_xor(ss, 4);
                ss += __shfl_xor(ss, 8);
                float rs = __builtin_amdgcn_rcpf(ss);
                float a0 = e0 * rs, a1 = e1 * rs;
                a0s += a0; a1s += a1;
                p0[r] = (short)f2bf(a0);
                p1[r] = (short)f2bf(a1);
            }
            suma[0] += a0s; suma[1] += a1s;
            // a_lds[k][n] (n contiguous): 4 consecutive n per lane -> 8 B write
            *(bf16x4*)(a_lds + l15*A_STRIDE        + s*16 + quad*4) = p0;
            *(bf16x4*)(a_lds + (16 + l15)*A_STRIDE + s*16 + quad*4) = p1;
        }

        // A2 fragments: A[m=k][kdim=n] -> contiguous 16 B from a_lds
        bf16x8 a2[2];
#pragma unroll
        for (int kt = 0; kt < 2; ++kt)
            a2[kt] = *(bf16x8*)(a_lds + (kt*16 + l15)*A_STRIDE + quad*8);

        // GEMM2: v += a^T r ; B[kdim=n][col=c] via scalar LDS reads
#pragma unroll
        for (int ct = 0; ct < 4; ++ct) {
            bf16x8 b2;
#pragma unroll
            for (int j = 0; j < 8; ++j)
                b2[j] = r_lds[(quad*8 + j)*R_STRIDE + ct*16 + l15];
#pragma unroll
            for (int kt = 0; kt < 2; ++kt)
                acc[kt][ct] = __builtin_amdgcn_mfma_f32_16x16x32_bf16(a2[kt], b2, acc[kt][ct], 0, 0, 0);
        }

        if (it < 7) {
#pragma unroll
            for (int s = 0; s < 2; ++s)
#pragma unroll
                for (int cc = 0; cc < 2; ++cc) {
                    cur[s][cc][0] = nxt[s][cc][0];
                    cur[s][cc][1] = nxt[s][cc][1];
                }
        }
    }

    // suma held per-lane for k = l15 (+16): fold the 4 quads together
#pragma unroll
    for (int kt = 0; kt < 2; ++kt) {
        suma[kt] += __shfl_xor(suma[kt], 16);
        suma[kt] += __shfl_xor(suma[kt], 32);
    }

    // cross-wave log-tree reduction, aliasing the staging LDS as fp32 buffers
    float* vbuf = (float*)smem;
    __syncthreads();
#pragma unroll
    for (int step = 4; step >= 1; step >>= 1) {
        if (wave >= step && wave < 2*step) {
            float* dst = vbuf + (wave - step) * (32 * VB_STRIDE);
#pragma unroll
            for (int kt = 0; kt < 2; ++kt)
#pragma unroll
                for (int ct = 0; ct < 4; ++ct)
#pragma unroll
                    for (int r = 0; r < 4; ++r)
                        dst[(kt*16 + quad*4 + r)*VB_STRIDE + ct*16 + l15] = acc[kt][ct][r];
            if (lane < 16) {
                suma_buf[wave - step][lane]      = suma[0];
                suma_buf[wave - step][lane + 16] = suma[1];
            }
        }
        __syncthreads();
        if (wave < step) {
            const float* src = vbuf + wave * (32 * VB_STRIDE);
#pragma unroll
            for (int kt = 0; kt < 2; ++kt)
#pragma unroll
                for (int ct = 0; ct < 4; ++ct)
#pragma unroll
                    for (int r = 0; r < 4; ++r)
                        acc[kt][ct][r] += src[(kt*16 + quad*4 + r)*VB_STRIDE + ct*16 + l15];
            suma[0] += suma_buf[wave][l15];
            suma[1] += suma_buf[wave][l15 + 16];
        }
        __syncthreads();
    }

    // wave 0: v - suma[k]*cent[k][c], store fp32
    if (wave == 0) {
        float* op = out + (size_t)m * (32*64);
#pragma unroll
        for (int kt = 0; kt < 2; ++kt) {
#pragma unroll
            for (int r = 0; r < 4; ++r) {
                const int k = kt*16 + quad*4 + r;
                const float su = __shfl(suma[kt], quad*4 + r);
#pragma unroll
                for (int ct = 0; ct < 4; ++ct) {
                    const int c = ct*16 + l15;
                    const float cv = cent[k*64 + c];
                    op[k*64 + c] = acc[kt][ct][r] - su * cv;
                }
            }
        }
    }
}

extern "C" void kernel_launch(void* const* d_in, const int* in_sizes, int n_in,
                              void* d_out, int out_size, void* d_ws, size_t ws_size,
                              hipStream_t stream) {
    (void)in_sizes; (void)n_in; (void)out_size; (void)d_ws; (void)ws_size;
    const float* R = (const float*)d_in[0];   // R_seq (8,32,2048,64) fp32
    const float* W = (const float*)d_in[1];   // W (32,64) fp32
    const float* b = (const float*)d_in[2];   // b (32,) fp32
    const float* c = (const float*)d_in[3];   // centroids (32,64) fp32
    float* out = (float*)d_out;               // (8,32,32,64) fp32

    hipLaunchKernelGGL(netvlad_fused, dim3(256), dim3(512), 0, stream, R, W, b, c, out);
}

// Round 4
// 202.103 us; speedup vs baseline: 1.0067x; 1.0067x over previous
//
#include <hip/hip_runtime.h>
#include <stdint.h>

typedef __attribute__((ext_vector_type(8))) short bf16x8;
typedef __attribute__((ext_vector_type(4))) short bf16x4;
typedef __attribute__((ext_vector_type(4))) float f32x4;

#define WAVES 8
#define R_STRIDE 72                    // shorts; 144 B rows (16B aligned)
#define A_STRIDE 40                    // shorts; 80 B rows (16B aligned)
#define R_LDS_SHORTS (32 * R_STRIDE)   // 2304
#define A_LDS_SHORTS (32 * A_STRIDE)   // 1280
#define WAVE_LDS (R_LDS_SHORTS + A_LDS_SHORTS)  // 3584 shorts = 7168 B per wave
#define VB_STRIDE 68                   // padded fp32 row stride for reduction buffers

static __device__ __forceinline__ unsigned short f2bf(float f) {
    union { float f; unsigned int i; } x; x.f = f;
    unsigned int i = x.i;
    return (unsigned short)((i + 0x7FFFu + ((i >> 16) & 1u)) >> 16);  // RNE
}

static __device__ __forceinline__ bf16x8 cvt8(float4 a, float4 b) {
    bf16x8 r;
    r[0] = (short)f2bf(a.x); r[1] = (short)f2bf(a.y);
    r[2] = (short)f2bf(a.z); r[3] = (short)f2bf(a.w);
    r[4] = (short)f2bf(b.x); r[5] = (short)f2bf(b.y);
    r[6] = (short)f2bf(b.z); r[7] = (short)f2bf(b.w);
    return r;
}

// Sum across the 16 lanes of a DPP row (all lanes end with the total).
// VALU-pipe rotation reduction: row_ror:8,4,2,1  (0x128,0x124,0x122,0x121).
static __device__ __forceinline__ float row_sum16(float x) {
    union fi { float f; int i; };
    fi a, b; a.f = x;
    b.i = __builtin_amdgcn_mov_dpp(a.i, 0x128, 0xf, 0xf, false); a.f += b.f;
    b.i = __builtin_amdgcn_mov_dpp(a.i, 0x124, 0xf, 0xf, false); a.f += b.f;
    b.i = __builtin_amdgcn_mov_dpp(a.i, 0x122, 0xf, 0xf, false); a.f += b.f;
    b.i = __builtin_amdgcn_mov_dpp(a.i, 0x121, 0xf, 0xf, false); a.f += b.f;
    return a.f;
}

// r_lds bank swizzle: logical (n, c) -> short index n*R_STRIDE + (c ^ ((n>>3&3)<<4)).
// Staging writes stay 16B-aligned b128 (XOR permutes 16-elem column groups);
// GEMM2's gather (fixed j,ct: lanes quad,l15) hits banks (ct^quad)*8 + l15/2
// -> all 32 banks, 2 lanes/bank = conflict-free.

__global__ __launch_bounds__(512, 2)
void netvlad_fused(const float* __restrict__ R,
                   const float* __restrict__ W,
                   const float* __restrict__ bias,
                   const float* __restrict__ cent,
                   float* __restrict__ out)
{
    __shared__ short smem[WAVES * WAVE_LDS];   // 57344 B; reused as fp32 reduction bufs
    __shared__ float suma_buf[4][32];

    const int tid  = threadIdx.x;
    const int wave = tid >> 6;
    const int lane = tid & 63;
    const int l15  = lane & 15;
    const int quad = lane >> 4;
    const int m    = blockIdx.x;

    short* r_lds = smem + wave * WAVE_LDS;
    short* a_lds = r_lds + R_LDS_SHORTS;

    const float* Rm = R + (size_t)m * (2048 * 64);

    // W fragments (B-operand of GEMM1): lane reads W row (kt*16+l15),
    // cols cc*32+quad*8..+7 : two float4 loads, convert to bf16.
    bf16x8 wf[2][2];
#pragma unroll
    for (int kt = 0; kt < 2; ++kt)
#pragma unroll
        for (int cc = 0; cc < 2; ++cc) {
            const float* wp = W + (kt*16 + l15)*64 + cc*32 + quad*8;
            wf[kt][cc] = cvt8(*(const float4*)wp, *(const float4*)(wp + 4));
        }

    float bval[2];
    bval[0] = bias[l15];
    bval[1] = bias[16 + l15];

    f32x4 acc[2][4];   // v accumulator tiles [ktile][ctile], D-layout
#pragma unroll
    for (int kt = 0; kt < 2; ++kt)
#pragma unroll
        for (int ct = 0; ct < 4; ++ct)
            acc[kt][ct] = (f32x4){0.f, 0.f, 0.f, 0.f};
    float suma[2] = {0.f, 0.f};

    // prefetch iter 0 (wave w starts at rows w*32): raw fp32, [s][cc][half]
    float4 cur[2][2][2];
#pragma unroll
    for (int s = 0; s < 2; ++s)
#pragma unroll
        for (int cc = 0; cc < 2; ++cc) {
            const float* rp = Rm + (size_t)(wave*32 + s*16 + l15)*64 + cc*32 + quad*8;
            cur[s][cc][0] = *(const float4*)rp;
            cur[s][cc][1] = *(const float4*)(rp + 4);
        }

#pragma unroll
    for (int it = 0; it < 8; ++it) {
        float4 nxt[2][2][2];
        if (it < 7) {
            const int n0n = ((it+1)*WAVES + wave) * 32;
#pragma unroll
            for (int s = 0; s < 2; ++s)
#pragma unroll
                for (int cc = 0; cc < 2; ++cc) {
                    const float* rp = Rm + (size_t)(n0n + s*16 + l15)*64 + cc*32 + quad*8;
                    nxt[s][cc][0] = *(const float4*)rp;
                    nxt[s][cc][1] = *(const float4*)(rp + 4);
                }
        }

        // convert to bf16 A-frags and stage r tile to per-wave LDS (swizzled)
        bf16x8 af[2][2];
#pragma unroll
        for (int s = 0; s < 2; ++s) {
            const int g = (s*2 + (l15 >> 3)) & 3;          // (n>>3)&3 for n=s*16+l15
#pragma unroll
            for (int cc = 0; cc < 2; ++cc) {
                af[s][cc] = cvt8(cur[s][cc][0], cur[s][cc][1]);
                const int c0s = (cc*32 + quad*8) ^ (g << 4);
                *(bf16x8*)(r_lds + (s*16 + l15)*R_STRIDE + c0s) = af[s][cc];
            }
        }

        // GEMM1: logits (32 rows x 32 k), 8 MFMAs
        f32x4 d1[2][2];
#pragma unroll
        for (int s = 0; s < 2; ++s)
#pragma unroll
            for (int kt = 0; kt < 2; ++kt) {
                f32x4 d = (f32x4){0.f, 0.f, 0.f, 0.f};
                d = __builtin_amdgcn_mfma_f32_16x16x32_bf16(af[s][0], wf[kt][0], d, 0, 0, 0);
                d = __builtin_amdgcn_mfma_f32_16x16x32_bf16(af[s][1], wf[kt][1], d, 0, 0, 0);
                d1[s][kt] = d;
            }

        // softmax over k (row = s*16 + quad*4 + r, k = kt*16 + l15)
#pragma unroll
        for (int s = 0; s < 2; ++s) {
            bf16x4 p0, p1;
            float a0s = 0.f, a1s = 0.f;
#pragma unroll
            for (int r = 0; r < 4; ++r) {
                float l0 = d1[s][0][r] + bval[0];
                float l1 = d1[s][1][r] + bval[1];
                float e0 = __expf(l0);
                float e1 = __expf(l1);
                float ss = row_sum16(e0 + e1);             // VALU DPP, off the LDS pipe
                float rs = __builtin_amdgcn_rcpf(ss);
                float a0 = e0 * rs, a1 = e1 * rs;
                a0s += a0; a1s += a1;
                p0[r] = (short)f2bf(a0);
                p1[r] = (short)f2bf(a1);
            }
            suma[0] += a0s; suma[1] += a1s;
            // a_lds[k][n] (n contiguous): 4 consecutive n per lane -> 8 B write
            *(bf16x4*)(a_lds + l15*A_STRIDE        + s*16 + quad*4) = p0;
            *(bf16x4*)(a_lds + (16 + l15)*A_STRIDE + s*16 + quad*4) = p1;
        }

        // A2 fragments: A[m=k][kdim=n] -> contiguous 16 B from a_lds
        bf16x8 a2[2];
#pragma unroll
        for (int kt = 0; kt < 2; ++kt)
            a2[kt] = *(bf16x8*)(a_lds + (kt*16 + l15)*A_STRIDE + quad*8);

        // GEMM2: v += a^T r ; B[kdim=n][col=c] gathered from swizzled r_lds.
        // element (n=quad*8+j, c=ct*16+l15) lives at n*R_STRIDE + (ct^quad)*16 + l15
#pragma unroll
        for (int ct = 0; ct < 4; ++ct) {
            const short* bp = r_lds + (quad*8)*R_STRIDE + ((ct ^ quad) << 4) + l15;
            bf16x8 b2;
#pragma unroll
            for (int j = 0; j < 8; ++j)
                b2[j] = bp[j*R_STRIDE];
#pragma unroll
            for (int kt = 0; kt < 2; ++kt)
                acc[kt][ct] = __builtin_amdgcn_mfma_f32_16x16x32_bf16(a2[kt], b2, acc[kt][ct], 0, 0, 0);
        }

        if (it < 7) {
#pragma unroll
            for (int s = 0; s < 2; ++s)
#pragma unroll
                for (int cc = 0; cc < 2; ++cc) {
                    cur[s][cc][0] = nxt[s][cc][0];
                    cur[s][cc][1] = nxt[s][cc][1];
                }
        }
    }

    // suma held per-lane for k = l15 (+16): fold the 4 quads together
#pragma unroll
    for (int kt = 0; kt < 2; ++kt) {
        suma[kt] += __shfl_xor(suma[kt], 16);
        suma[kt] += __shfl_xor(suma[kt], 32);
    }

    // cross-wave log-tree reduction, aliasing the staging LDS as fp32 buffers
    float* vbuf = (float*)smem;
    __syncthreads();
#pragma unroll
    for (int step = 4; step >= 1; step >>= 1) {
        if (wave >= step && wave < 2*step) {
            float* dst = vbuf + (wave - step) * (32 * VB_STRIDE);
#pragma unroll
            for (int kt = 0; kt < 2; ++kt)
#pragma unroll
                for (int ct = 0; ct < 4; ++ct)
#pragma unroll
                    for (int r = 0; r < 4; ++r)
                        dst[(kt*16 + quad*4 + r)*VB_STRIDE + ct*16 + l15] = acc[kt][ct][r];
            if (lane < 16) {
                suma_buf[wave - step][lane]      = suma[0];
                suma_buf[wave - step][lane + 16] = suma[1];
            }
        }
        __syncthreads();
        if (wave < step) {
            const float* src = vbuf + wave * (32 * VB_STRIDE);
#pragma unroll
            for (int kt = 0; kt < 2; ++kt)
#pragma unroll
                for (int ct = 0; ct < 4; ++ct)
#pragma unroll
                    for (int r = 0; r < 4; ++r)
                        acc[kt][ct][r] += src[(kt*16 + quad*4 + r)*VB_STRIDE + ct*16 + l15];
            suma[0] += suma_buf[wave][l15];
            suma[1] += suma_buf[wave][l15 + 16];
        }
        __syncthreads();
    }

    // wave 0: v - suma[k]*cent[k][c], store fp32
    if (wave == 0) {
        float* op = out + (size_t)m * (32*64);
#pragma unroll
        for (int kt = 0; kt < 2; ++kt) {
#pragma unroll
            for (int r = 0; r < 4; ++r) {
                const int k = kt*16 + quad*4 + r;
                const float su = __shfl(suma[kt], quad*4 + r);
#pragma unroll
                for (int ct = 0; ct < 4; ++ct) {
                    const int c = ct*16 + l15;
                    const float cv = cent[k*64 + c];
                    op[k*64 + c] = acc[kt][ct][r] - su * cv;
                }
            }
        }
    }
}

extern "C" void kernel_launch(void* const* d_in, const int* in_sizes, int n_in,
                              void* d_out, int out_size, void* d_ws, size_t ws_size,
                              hipStream_t stream) {
    (void)in_sizes; (void)n_in; (void)out_size; (void)d_ws; (void)ws_size;
    const float* R = (const float*)d_in[0];   // R_seq (8,32,2048,64) fp32
    const float* W = (const float*)d_in[1];   // W (32,64) fp32
    const float* b = (const float*)d_in[2];   // b (32,) fp32
    const float* c = (const float*)d_in[3];   // centroids (32,64) fp32
    float* out = (float*)d_out;               // (8,32,32,64) fp32

    hipLaunchKernelGGL(netvlad_fused, dim3(256), dim3(512), 0, stream, R, W, b, c, out);
}